// Round 2
// baseline (651.246 us; speedup 1.0000x reference)
//
#include <hip/hip_runtime.h>

#define IMG_H 4200
#define IMG_W 3200
#define HF 84
#define WF 64
#define NB 8
#define BAND 2   // feat rows (head rows) per block

typedef const __attribute__((address_space(1))) unsigned int* gl_p;
typedef __attribute__((address_space(3))) unsigned int* lds_p;

__device__ __forceinline__ void gl_lds16(const void* g, void* l) {
    __builtin_amdgcn_global_load_lds((gl_p)g, (lds_p)l, 16, 0, 0);
}

// Fused: 50x50/s50 conv (1->2ch) + 3x3 box/cls heads + softmax + anchors + mask.
// One block per (image, 2-feat-row band). Conv recomputes 1 halo row each side
// (2x input re-read) so NO global workspace is needed -> no feats buffer, no d_ws.
// X streams through double-buffered LDS (2 rows/stage) via global_load_lds;
// conv weights are wave-uniform LDS broadcasts; feats tile lives in LDS.
__global__ __launch_bounds__(256) void fused_kernel(
    const float* __restrict__ X, const float* __restrict__ cw,
    const float* __restrict__ cb, const float* __restrict__ bw,
    const float* __restrict__ bb, const float* __restrict__ clw,
    const float* __restrict__ clb, float* __restrict__ out) {
    __shared__ float2 w2[2500];                      // (ch0,ch1) per (ky,kx)
    __shared__ __align__(16) float4 rowbuf[2][1600]; // 2 input rows = 6400 floats, dbuf
    __shared__ float2 feats[BAND + 2][WF];           // conv out tile incl. halo
    __shared__ float2 part[3][WF];                   // cross-wave partials
    __shared__ float s_bw[648];                      // [36][2][3][3]
    __shared__ float s_bb[36];
    __shared__ float s_cw[36];                       // [2][2][3][3]
    __shared__ float s_cb[2];

    const int tid = threadIdx.x;
    const int wave = tid >> 6;
    const int lane = tid & 63;
    const int n = blockIdx.y;
    const int r0 = blockIdx.x * BAND;

    for (int e = tid; e < 2500; e += 256) w2[e] = make_float2(cw[e], cw[2500 + e]);
    for (int e = tid; e < 648; e += 256) s_bw[e] = bw[e];
    if (tid < 36) { s_bb[tid] = bb[tid]; s_cw[tid] = clw[tid]; }
    if (tid < 2) s_cb[tid] = clb[tid];
    ((float2*)feats)[tid] = make_float2(0.f, 0.f);   // (BAND+2)*WF == 256

    const int fr_lo = (r0 == 0) ? 0 : r0 - 1;
    const int fr_hi = (r0 + BAND + 1 > HF) ? HF : r0 + BAND + 1;
    const int ir0 = fr_lo * 50;                      // first input row (even)
    const int nst = (fr_hi * 50 - ir0) >> 1;         // 2 input rows per stage

    const float* Xb = X + ((size_t)n * IMG_H + ir0) * IMG_W;

    // prologue: stage input-row pair 0 into buf 0 (1600 float4)
    {
        const float4* sp = (const float4*)Xb;
        float4* d = rowbuf[0];
#pragma unroll
        for (int k = 0; k < 6; ++k) gl_lds16(sp + tid + 256 * k, d + tid + 256 * k);
        if (tid < 64) gl_lds16(sp + tid + 1536, d + tid + 1536);
    }
    __syncthreads();  // vmcnt(0) drained before barrier -> pair 0 resident

    const int kx0 = wave * 12 + (wave < 2 ? wave : 2);  // 0,13,26,38
    const int len = (wave < 2) ? 13 : 12;
    const float cbias0 = cb[0], cbias1 = cb[1];
    float a0 = 0.f, a1 = 0.f;

    for (int s = 0; s < nst; ++s) {
        if (s + 1 < nst) {  // prefetch next row pair
            const float4* sp = (const float4*)(Xb + (size_t)(s + 1) * 6400);
            float4* d = rowbuf[(s + 1) & 1];
#pragma unroll
            for (int k = 0; k < 6; ++k) gl_lds16(sp + tid + 256 * k, d + tid + 256 * k);
            if (tid < 64) gl_lds16(sp + tid + 1536, d + tid + 1536);
        }
        const float* rA = (const float*)rowbuf[s & 1];
        const float* rB = rA + 3200;
        const int ky2 = (ir0 + 2 * s) % 50;          // even row-in-window
        const float2* wA = &w2[ky2 * 50];
        const float2* wB = wA + 50;
#pragma unroll
        for (int t = 0; t < 13; ++t) {
            if (t < len) {                            // wave-uniform predicate
                const int kx = kx0 + t;
                const float xa = rA[lane * 50 + kx];  // 4-way bank alias, ok
                const float2 wa = wA[kx];             // uniform -> broadcast
                a0 = fmaf(xa, wa.x, a0);
                a1 = fmaf(xa, wa.y, a1);
            }
        }
#pragma unroll
        for (int t = 0; t < 13; ++t) {
            if (t < len) {
                const int kx = kx0 + t;
                const float xb = rB[lane * 50 + kx];
                const float2 wb = wB[kx];
                a0 = fmaf(xb, wb.x, a0);
                a1 = fmaf(xb, wb.y, a1);
            }
        }
        if (ky2 == 48) {  // finished a feat row: cross-wave reduce into feats tile
            if (wave > 0) part[wave - 1][lane] = make_float2(a0, a1);
            __syncthreads();
            if (wave == 0) {
                float s0 = a0, s1 = a1;
#pragma unroll
                for (int w = 0; w < 3; ++w) { s0 += part[w][lane].x; s1 += part[w][lane].y; }
                const int fr = (ir0 + 2 * s) / 50;
                feats[fr - r0 + 1][lane] = make_float2(s0 + cbias0, s1 + cbias1);
            }
            a0 = 0.f; a1 = 0.f;
        }
        __syncthreads();  // pair consumed; prefetched pair landed
    }

    // ---- head: 128 threads, one per (y, j) pixel of the band ----
    if (tid < BAND * WF) {
        const int j = lane;
        const int y = r0 + (tid >> 6);

        float f0[3][3], f1[3][3];
#pragma unroll
        for (int dy = 0; dy < 3; ++dy) {
            const int q = (tid >> 6) + dy;            // feats tile row (halo rows are zeroed)
#pragma unroll
            for (int dx = 0; dx < 3; ++dx) {
                const int xx = j + dx - 1;
                float2 v = (xx >= 0 && xx < WF) ? feats[q][xx] : make_float2(0.f, 0.f);
                f0[dy][dx] = v.x;
                f1[dy][dx] = v.y;
            }
        }

        // cls conv + softmax over 2 channels
        float c0 = s_cb[0], c1 = s_cb[1];
#pragma unroll
        for (int ky = 0; ky < 3; ++ky)
#pragma unroll
            for (int kx = 0; kx < 3; ++kx) {
                int k = ky * 3 + kx;
                c0 = fmaf(f0[ky][kx], s_cw[k], c0);
                c0 = fmaf(f1[ky][kx], s_cw[9 + k], c0);
                c1 = fmaf(f0[ky][kx], s_cw[18 + k], c1);
                c1 = fmaf(f1[ky][kx], s_cw[27 + k], c1);
            }
        float mx = fmaxf(c0, c1);
        float e0 = expf(c0 - mx), e1 = expf(c1 - mx);
        float p1 = e1 / (e0 + e1);
        const float maskf = (p1 > 0.95f) ? 1.f : 0.f;

        const float gx = (j + 0.5f) * 50.f;
        const float gy = (y + 0.5f) * 50.f;
        const float wsv[9] = {22.627417f, 16.f, 11.3137085f,
                              45.254834f, 32.f, 22.627417f,
                              90.509668f, 64.f, 45.254834f};
        const float hsv[9] = {11.3137085f, 16.f, 22.627417f,
                              22.627417f, 32.f, 45.254834f,
                              45.254834f, 64.f, 90.509668f};

        const int p = (n * HF + y) * WF + j;
        float4* outp = (float4*)out + (size_t)p * 9;
#pragma unroll
        for (int a = 0; a < 9; ++a) {
            float o[4];
#pragma unroll
            for (int c = 0; c < 4; ++c) {
                const int ch = a * 4 + c;
                const float* w = &s_bw[ch * 18];
                float acc = s_bb[ch];
#pragma unroll
                for (int ky = 0; ky < 3; ++ky)
#pragma unroll
                    for (int kx = 0; kx < 3; ++kx) {
                        int k = ky * 3 + kx;
                        acc = fmaf(f0[ky][kx], w[k], acc);
                        acc = fmaf(f1[ky][kx], w[9 + k], acc);
                    }
                o[c] = acc;
            }
            const float hw = 0.5f * wsv[a], hh = 0.5f * hsv[a];
            float x1 = fminf(fmaxf(gx - hw + o[0], 0.f), 3200.f);
            float y1 = fminf(fmaxf(gy - hh + o[1], 0.f), 4200.f);
            float x2 = fminf(fmaxf(gx + hw + o[2], 0.f), 3200.f);
            float y2 = fminf(fmaxf(gy + hh + o[3], 0.f), 4200.f);
            outp[a] = make_float4(x1 * maskf, y1 * maskf, x2 * maskf, y2 * maskf);
        }
    }
}

extern "C" void kernel_launch(void* const* d_in, const int* in_sizes, int n_in,
                              void* d_out, int out_size, void* d_ws, size_t ws_size,
                              hipStream_t stream) {
    const float* X   = (const float*)d_in[0];
    const float* cw  = (const float*)d_in[1];
    const float* cb  = (const float*)d_in[2];
    const float* bw  = (const float*)d_in[3];
    const float* bb  = (const float*)d_in[4];
    const float* clw = (const float*)d_in[5];
    const float* clb = (const float*)d_in[6];
    float* out = (float*)d_out;
    (void)d_ws; (void)ws_size;  // workspace intentionally unused

    // 42 bands x 8 images = 336 blocks, one kernel, no workspace round-trip
    fused_kernel<<<dim3(HF / BAND, NB), 256, 0, stream>>>(X, cw, cb, bw, bb, clw, clb, out);
}